// Round 3
// baseline (318.520 us; speedup 1.0000x reference)
//
#include <hip/hip_runtime.h>

#define S_DIM 4
#define A_DIM 64
#define B_DIM 2048
#define D_DIM 384
#define H1D 128
#define H2D 128
#define H3D 64
#define MT 64   // batch rows per block

typedef __attribute__((ext_vector_type(8))) short short8;
typedef __attribute__((ext_vector_type(4))) float float4v;

__device__ __forceinline__ unsigned short f2bf(float f) {
  unsigned u = __float_as_uint(f);
  u += 0x7FFFu + ((u >> 16) & 1u);   // round-to-nearest-even
  return (unsigned short)(u >> 16);
}

__device__ __forceinline__ void store_bf4(unsigned short* p, float4v v) {
  union { unsigned short s[4]; uint2 u; } t;
  t.s[0] = f2bf(v[0]); t.s[1] = f2bf(v[1]);
  t.s[2] = f2bf(v[2]); t.s[3] = f2bf(v[3]);
  *(uint2*)p = t.u;   // one ds_write_b64
}

// LDS-tiled transpose + bf16 convert: coalesced reads AND writes.
// out layouts (N-major): W0T[s][h1][d], W1T[s][h2][h1], W2T[s][h3][h2]
__global__ __launch_bounds__(256) void prep_weights(
    const float* __restrict__ W0, const float* __restrict__ W1,
    const float* __restrict__ W2,
    unsigned short* __restrict__ W0T, unsigned short* __restrict__ W1T,
    unsigned short* __restrict__ W2T) {
  __shared__ float tile[32][33];
  int b = blockIdx.x;
  const float* src; unsigned short* dst; int R, C, dt, ht, s;
  if (b < 192) {                 // W0: 4 x 12 x 4 tiles
    s = b / 48; int t = b % 48; dt = t / 4; ht = t % 4;
    src = W0 + s * D_DIM * H1D; dst = W0T + s * H1D * D_DIM; R = D_DIM; C = H1D;
  } else if (b < 256) {          // W1: 4 x 4 x 4
    int bb = b - 192; s = bb / 16; int t = bb % 16; dt = t / 4; ht = t % 4;
    src = W1 + s * H1D * H2D; dst = W1T + s * H2D * H1D; R = H1D; C = H2D;
  } else {                       // W2: 4 x 4 x 2
    int bb = b - 256; s = bb / 8; int t = bb % 8; dt = t / 2; ht = t % 2;
    src = W2 + s * H2D * H3D; dst = W2T + s * H3D * H2D; R = H2D; C = H3D;
  }
  int tx = threadIdx.x & 31, ty = threadIdx.x >> 5;
#pragma unroll
  for (int k = 0; k < 4; ++k)
    tile[ty + 8 * k][tx] = src[(size_t)(dt * 32 + ty + 8 * k) * C + ht * 32 + tx];
  __syncthreads();
#pragma unroll
  for (int k = 0; k < 4; ++k)
    dst[(size_t)(ht * 32 + ty + 8 * k) * R + dt * 32 + tx] = f2bf(tile[tx][ty + 8 * k]);
}

// Block = 1 atom x 64 batch rows. Single-shot x staging (full 384-k in LDS),
// activation buffers aliased into the same region. 5 barriers total.
__global__ __launch_bounds__(256, 3) void mlp_fused(
    const float* __restrict__ x, const int* __restrict__ species,
    const unsigned short* __restrict__ W0T, const unsigned short* __restrict__ W1T,
    const unsigned short* __restrict__ W2T,
    const float* __restrict__ b0, const float* __restrict__ b1,
    const float* __restrict__ b2, const float* __restrict__ W3,
    const float* __restrict__ b3, float* __restrict__ out) {
  // bufA serves as: xs[64][392] (L0 input), then H0[64][136] (region0),
  // H1[64][136] (region1), then H2 float[64][68] (region0 again).
  // 392-short row stride: 16B-aligned b128 reads, <=2-way bank aliasing.
  __shared__ __align__(16) unsigned short bufA[MT * 392];
  __shared__ __align__(16) float W3s[H3D];

  unsigned short* xs = bufA;                 // [64][392]
  unsigned short* H0 = bufA;                 // [64][136]
  unsigned short* H1 = bufA + MT * 136;      // [64][136]
  float* H2 = (float*)bufA;                  // [64][68]

  const int a = blockIdx.y;
  const int brow0 = blockIdx.x * MT;
  const int sp = species[a];
  const int tid = threadIdx.x;
  const int wave = tid >> 6;
  const int lane = tid & 63;
  const int q = lane >> 4;   // A/B k-quad, C/D row-quad
  const int r = lane & 15;   // A row / B col / C col

  if (tid < H3D) W3s[tid] = W3[sp * H3D + tid];

  const float4v zero = {0.f, 0.f, 0.f, 0.f};

  // ---------------- stage x: 64 rows x 384 cols fp32 -> bf16 LDS, one shot ----------
  const int srow = tid >> 2;           // thread's row
  const int c4 = tid & 3;              // 16B piece within 64B cluster
  const float* xrow = x + ((size_t)(brow0 + srow) * A_DIM + a) * D_DIM + c4 * 4;
  unsigned short* xdst = xs + srow * 392 + c4 * 4;

  const unsigned short* w0base =
      W0T + (size_t)sp * H1D * D_DIM + (wave * 32 + r) * D_DIM + q * 8;

  float4v xva[8], xvb[8];
#pragma unroll
  for (int j = 0; j < 8; ++j) xva[j] = *(const float4v*)(xrow + j * 16);
#pragma unroll
  for (int j = 0; j < 8; ++j) xvb[j] = *(const float4v*)(xrow + (j + 8) * 16);
  // L0 stage-0 B-frags issued behind the x loads (L2-hot)
  short8 bf0[4][2];
#pragma unroll
  for (int kk = 0; kk < 4; ++kk)
#pragma unroll
    for (int n = 0; n < 2; ++n)
      bf0[kk][n] = *(const short8*)(w0base + n * 16 * D_DIM + kk * 32);
#pragma unroll
  for (int j = 0; j < 8; ++j) store_bf4(xdst + j * 16, xva[j]);
#pragma unroll
  for (int j = 0; j < 8; ++j) xva[j] = *(const float4v*)(xrow + (j + 16) * 16);
#pragma unroll
  for (int j = 0; j < 8; ++j) store_bf4(xdst + (j + 8) * 16, xvb[j]);
#pragma unroll
  for (int j = 0; j < 8; ++j) store_bf4(xdst + (j + 16) * 16, xva[j]);
  __syncthreads();   // (1) xs complete

  // ---------------- layer 0: [64x384] @ [384x128], 12 k-steps, no barriers ----------
  float4v acc0[4][2];
#pragma unroll
  for (int g = 0; g < 4; ++g) { acc0[g][0] = zero; acc0[g][1] = zero; }
#pragma unroll
  for (int st = 0; st < 3; ++st) {
    short8 bfs[4][2];
    if (st == 0) {
#pragma unroll
      for (int kk = 0; kk < 4; ++kk) { bfs[kk][0] = bf0[kk][0]; bfs[kk][1] = bf0[kk][1]; }
    } else {
#pragma unroll
      for (int kk = 0; kk < 4; ++kk)
#pragma unroll
        for (int n = 0; n < 2; ++n)
          bfs[kk][n] = *(const short8*)(w0base + n * 16 * D_DIM + st * 128 + kk * 32);
    }
#pragma unroll
    for (int g = 0; g < 4; ++g)
#pragma unroll
      for (int kk = 0; kk < 4; ++kk) {
        short8 af = *(const short8*)(xs + (g * 16 + r) * 392 + st * 128 + kk * 32 + q * 8);
        acc0[g][0] = __builtin_amdgcn_mfma_f32_16x16x32_bf16(af, bfs[kk][0], acc0[g][0], 0, 0, 0);
        acc0[g][1] = __builtin_amdgcn_mfma_f32_16x16x32_bf16(af, bfs[kk][1], acc0[g][1], 0, 0, 0);
      }
  }
  __syncthreads();   // (2) all xs reads done; region0 about to be overwritten with H0
  {
    const float* b0p = b0 + sp * H1D;
#pragma unroll
    for (int n = 0; n < 2; ++n) {
      float bias = b0p[wave * 32 + n * 16 + r];
#pragma unroll
      for (int g = 0; g < 4; ++g)
#pragma unroll
        for (int i = 0; i < 4; ++i) {
          float y = acc0[g][n][i] + bias;
          H0[(g * 16 + q * 4 + i) * 136 + wave * 32 + n * 16 + r] = f2bf(__expf(-y * y));
        }
    }
  }
  __syncthreads();   // (3) H0 complete

  // ---------------- layer 1: [64x128] @ [128x128]; H0 -> H1 (disjoint regions) -------
  {
    float4v acc1[4][2];
#pragma unroll
    for (int g = 0; g < 4; ++g) { acc1[g][0] = zero; acc1[g][1] = zero; }
    const unsigned short* w1base =
        W1T + (size_t)sp * H2D * H1D + (wave * 32 + r) * H1D + q * 8;
    short8 bf[4][2];
#pragma unroll
    for (int kk = 0; kk < 4; ++kk)
#pragma unroll
      for (int n = 0; n < 2; ++n)
        bf[kk][n] = *(const short8*)(w1base + n * 16 * H1D + kk * 32);
#pragma unroll
    for (int g = 0; g < 4; ++g)
#pragma unroll
      for (int kk = 0; kk < 4; ++kk) {
        short8 af = *(const short8*)(H0 + (g * 16 + r) * 136 + kk * 32 + q * 8);
        acc1[g][0] = __builtin_amdgcn_mfma_f32_16x16x32_bf16(af, bf[kk][0], acc1[g][0], 0, 0, 0);
        acc1[g][1] = __builtin_amdgcn_mfma_f32_16x16x32_bf16(af, bf[kk][1], acc1[g][1], 0, 0, 0);
      }
    const float* b1p = b1 + sp * H2D;
#pragma unroll
    for (int n = 0; n < 2; ++n) {
      float bias = b1p[wave * 32 + n * 16 + r];
#pragma unroll
      for (int g = 0; g < 4; ++g)
#pragma unroll
        for (int i = 0; i < 4; ++i) {
          float y = acc1[g][n][i] + bias;
          H1[(g * 16 + q * 4 + i) * 136 + wave * 32 + n * 16 + r] = f2bf(__expf(-y * y));
        }
    }
  }
  __syncthreads();   // (4) H1 complete (also fences all H0 reads)

  // ---------------- layer 2: [64x128] @ [128x64]; H1 -> H2 (region0) ----------------
  {
    float4v acc2[4];
#pragma unroll
    for (int g = 0; g < 4; ++g) acc2[g] = zero;
    const unsigned short* w2base =
        W2T + (size_t)sp * H3D * H2D + (wave * 16 + r) * H2D + q * 8;
    short8 bf[4];
#pragma unroll
    for (int kk = 0; kk < 4; ++kk)
      bf[kk] = *(const short8*)(w2base + kk * 32);
#pragma unroll
    for (int g = 0; g < 4; ++g)
#pragma unroll
      for (int kk = 0; kk < 4; ++kk) {
        short8 af = *(const short8*)(H1 + (g * 16 + r) * 136 + kk * 32 + q * 8);
        acc2[g] = __builtin_amdgcn_mfma_f32_16x16x32_bf16(af, bf[kk], acc2[g], 0, 0, 0);
      }
    float bias = b2[sp * H3D + wave * 16 + r];
#pragma unroll
    for (int g = 0; g < 4; ++g)
#pragma unroll
      for (int i = 0; i < 4; ++i) {
        float y = acc2[g][i] + bias;
        H2[(g * 16 + q * 4 + i) * 68 + wave * 16 + r] = __expf(-y * y);
      }
  }
  __syncthreads();   // (5) H2 complete

  // ---------------- layer 3: dot with W3[64] + cross-atom atomic sum ----------------
  {
    const int row = tid >> 2;
    const int seg = tid & 3;
    const float4v* h2p = (const float4v*)(H2 + row * 68 + seg * 16);
    const float4v* w3p = (const float4v*)(W3s + seg * 16);
    float4v sv = zero;
#pragma unroll
    for (int jj = 0; jj < 4; ++jj) sv += h2p[jj] * w3p[jj];
    float s = sv[0] + sv[1] + sv[2] + sv[3];
    s += __shfl_xor(s, 1);
    s += __shfl_xor(s, 2);
    if (seg == 0) atomicAdd(&out[brow0 + row], s + b3[sp]);
  }
}

extern "C" void kernel_launch(void* const* d_in, const int* in_sizes, int n_in,
                              void* d_out, int out_size, void* d_ws, size_t ws_size,
                              hipStream_t stream) {
  const float* x       = (const float*)d_in[0];
  const int*   species = (const int*)d_in[1];
  const float* W0 = (const float*)d_in[2];
  const float* b0 = (const float*)d_in[3];
  const float* W1 = (const float*)d_in[4];
  const float* b1 = (const float*)d_in[5];
  const float* W2 = (const float*)d_in[6];
  const float* b2 = (const float*)d_in[7];
  const float* W3 = (const float*)d_in[8];
  const float* b3 = (const float*)d_in[9];
  float* out = (float*)d_out;

  unsigned short* W0T = (unsigned short*)d_ws;
  unsigned short* W1T = W0T + S_DIM * H1D * D_DIM;
  unsigned short* W2T = W1T + S_DIM * H2D * H1D;

  hipMemsetAsync(d_out, 0, out_size * sizeof(float), stream);
  prep_weights<<<dim3(288), dim3(256), 0, stream>>>(W0, W1, W2, W0T, W1T, W2T);
  mlp_fused<<<dim3(B_DIM / MT, A_DIM), dim3(256), 0, stream>>>(
      x, species, W0T, W1T, W2T, b0, b1, b2, W3, b3, out);
}